// Round 7
// baseline (470.037 us; speedup 1.0000x reference)
//
#include <hip/hip_runtime.h>

typedef __attribute__((ext_vector_type(8))) short s8v;   // 8 x bf16 (4 VGPRs)
typedef __attribute__((ext_vector_type(4))) float f4v;   // MFMA acc
typedef unsigned short u16;
typedef unsigned int u32;

#define MTOT 8192   // B*T
#define CEMB 1024
#define C3   3072
#define TSEQ 2048
#define HDIM 64
#define NQT  32     // TSEQ/64
#define NPAIR 16
#define SCALE_LOG2 0.022542110013890054f   // (1/64) * log2(e)

__device__ __forceinline__ u16 f2bf(float f) {
  u32 u = __float_as_uint(f);
  u = (u + 0x7fffu + ((u >> 16) & 1u)) >> 16;  // RNE
  return (u16)u;
}

__device__ __forceinline__ void gload_lds16(const u16* g, u16* l) {
  __builtin_amdgcn_global_load_lds(
      (const __attribute__((address_space(1))) u32*)g,
      (__attribute__((address_space(3))) u32*)l, 16, 0, 0);
}

// ---------------- elementwise f32 -> bf16 ----------------
__global__ void cvt_f32_bf16(const float* __restrict__ in, u16* __restrict__ out, int n4) {
  int i = blockIdx.x * blockDim.x + threadIdx.x;
  if (i < n4) {
    float4 a = ((const float4*)in)[i];
    ushort4 o;
    o.x = f2bf(a.x); o.y = f2bf(a.y); o.z = f2bf(a.z); o.w = f2bf(a.w);
    ((ushort4*)out)[i] = o;
  }
}

// ---------------- transpose + cast: in[R][C] f32 -> out[C][R] bf16 ----------------
__global__ void transpose_cvt(const float* __restrict__ in, u16* __restrict__ out, int R, int C) {
  __shared__ float t[32][33];
  int c0 = blockIdx.x * 32, r0 = blockIdx.y * 32;
  int tx = threadIdx.x, ty = threadIdx.y;  // (32,8)
#pragma unroll
  for (int i = 0; i < 4; ++i)
    t[ty + 8 * i][tx] = in[(long)(r0 + ty + 8 * i) * C + c0 + tx];
  __syncthreads();
#pragma unroll
  for (int i = 0; i < 4; ++i)
    out[(long)(c0 + ty + 8 * i) * R + r0 + tx] = f2bf(t[tx][ty + 8 * i]);
}

// ---------------- V transpose: qkv V-part [t][d] -> vT[bh][d][t] ----------------
__global__ void vtrans(const u16* __restrict__ qkv, u16* __restrict__ vT) {
  __shared__ u16 t[64][72];
  const int bh = blockIdx.y, b = bh >> 4, h = bh & 15;
  const int t0 = blockIdx.x * 64;
  const int tid = threadIdx.x;
  {
    int tr = tid >> 2, dc = (tid & 3) * 16;
    const u16* src = qkv + ((long)(b * TSEQ + t0 + tr)) * C3 + 2048 + h * HDIM + dc;
    *(s8v*)&t[tr][dc] = *(const s8v*)src;
    *(s8v*)&t[tr][dc + 8] = *(const s8v*)(src + 8);
  }
  __syncthreads();
  {
    int dr = tid >> 2, tc = (tid & 3) * 16;
    s8v o0, o1;
#pragma unroll
    for (int i = 0; i < 8; ++i) {
      o0[i] = (short)t[tc + i][dr];
      o1[i] = (short)t[tc + 8 + i][dr];
    }
    u16* dst = vT + ((long)(bh * HDIM + dr)) * TSEQ + t0 + tc;
    *(s8v*)dst = o0;
    *(s8v*)(dst + 8) = o1;
  }
}

// ---------------- GEMM: C[M][N] = A[M][K] * BT[N][K]^T   (bf16 in, f32 acc) ----------------
template<int OUTF32>
__global__ __launch_bounds__(256, 3)
void gemm_bt(const u16* __restrict__ A, const u16* __restrict__ BT,
             void* __restrict__ Cout, int M, int N, int K) {
  __shared__ u16 sA[128 * 64];
  __shared__ u16 sB[128 * 64];
  const int tid = threadIdx.x;
  const int lane = tid & 63;
  const int w = tid >> 6;
  const int wr = w >> 1, wc = w & 1;
  const int blockM = blockIdx.y * 128;
  const int blockN = blockIdx.x * 128;

  f4v acc[4][4];
#pragma unroll
  for (int m = 0; m < 4; ++m)
#pragma unroll
    for (int n = 0; n < 4; ++n)
      acc[m][n] = (f4v){0.f, 0.f, 0.f, 0.f};

  const u16* aptr[4];
  const u16* bptr[4];
  int ldsoff[4];
#pragma unroll
  for (int i = 0; i < 4; ++i) {
    int ch = w * 4 + i;
    int L = ch * 1024 + lane * 16;
    int row = L >> 7;
    int pc = (L >> 4) & 7;
    int c = (pc ^ (row & 7)) * 8;
    ldsoff[i] = ch * 1024;
    aptr[i] = A + (long)(blockM + row) * K + c;
    bptr[i] = BT + (long)(blockN + row) * K + c;
  }

  for (int k0 = 0; k0 < K; k0 += 64) {
    __syncthreads();
#pragma unroll
    for (int i = 0; i < 4; ++i) {
      gload_lds16(aptr[i] + k0, (u16*)((char*)sA + ldsoff[i]));
      gload_lds16(bptr[i] + k0, (u16*)((char*)sB + ldsoff[i]));
    }
    __syncthreads();
#pragma unroll
    for (int ks = 0; ks < 2; ++ks) {
      s8v af[4], bfv[4];
      const int chunk = ks * 4 + (lane >> 4);
#pragma unroll
      for (int m = 0; m < 4; ++m) {
        int row = wr * 64 + m * 16 + (lane & 15);
        af[m] = *(const s8v*)((const char*)sA + row * 128 + ((chunk ^ (row & 7)) << 4));
      }
#pragma unroll
      for (int n = 0; n < 4; ++n) {
        int row = wc * 64 + n * 16 + (lane & 15);
        bfv[n] = *(const s8v*)((const char*)sB + row * 128 + ((chunk ^ (row & 7)) << 4));
      }
#pragma unroll
      for (int m = 0; m < 4; ++m)
#pragma unroll
        for (int n = 0; n < 4; ++n)
          acc[m][n] = __builtin_amdgcn_mfma_f32_16x16x32_bf16(af[m], bfv[n], acc[m][n], 0, 0, 0);
    }
  }

  const int rl = ((lane >> 4) & 3) * 4;
  const int cl = lane & 15;
#pragma unroll
  for (int m = 0; m < 4; ++m)
#pragma unroll
    for (int n = 0; n < 4; ++n)
#pragma unroll
      for (int j = 0; j < 4; ++j) {
        long r = blockM + wr * 64 + m * 16 + rl + j;
        long c = blockN + wc * 64 + n * 16 + cl;
        float v = acc[m][n][j];
        if (OUTF32)
          ((float*)Cout)[r * N + c] = v;
        else
          ((u16*)Cout)[r * N + c] = f2bf(v);
      }
}

// ---------------- flash attention (causal, muP scale 1/64) ----------------
// Pair-balanced: block (bh, p) handles q-tiles qa=p and qb=31-p, sharing staged K/V.
// Softmax in log2 domain (scale folds in log2(e)); defer-max rescale (THR=8);
// causal mask hoisted behind uniform branch (only diag tiles pay).
__global__ __launch_bounds__(256, 4)
void flash_attn(const u16* __restrict__ qkv, const u16* __restrict__ vT,
                u16* __restrict__ y) {
  __shared__ u16 sK[2][64 * 64];
  __shared__ u16 sV[2][64 * 64];
  __shared__ u16 sP[4][16 * 64];
  const int tid = threadIdx.x;
  const int lane = tid & 63;
  const int w = tid >> 6;
  const int g = lane >> 4, lo = lane & 15;
  const int bh = blockIdx.x;        // bh fastest -> all pair-blocks of a head on one XCD
  const int p = blockIdx.y;
  const int b = bh >> 4, h = bh & 15;
  const long rowbase = (long)b * TSEQ;
  const int qaT = p, qbT = NQT - 1 - p;
  const int nkt = qbT + 1;

  // staging: wave w owns chunks ch = w*2+i (i=0..1), rows w*16+i*8 .. +7
  const int srow = w * 16 + (lane >> 3);
  const int scol = ((lane & 7) ^ (lane >> 3)) * 8;  // pre-inverse-swizzled source col
  const u16* kS0 = qkv + (rowbase + srow) * C3 + 1024 + h * HDIM + scol;
  const u16* vS0 = vT + ((long)(bh * HDIM + srow)) * TSEQ + scol;
  u16* kD0 = &sK[0][w * 1024];
  u16* vD0 = &sV[0][w * 1024];

  auto stage = [&](int kt) {
    const int bufo = (kt & 1) * 4096;
    const long ka = (long)kt * 64 * C3;
    const int va = kt * 64;
#pragma unroll
    for (int i = 0; i < 2; ++i) {
      gload_lds16(kS0 + ka + i * 8 * C3, kD0 + bufo + i * 512);
      gload_lds16(vS0 + va + (long)i * 8 * TSEQ, vD0 + bufo + i * 512);
    }
  };

  s8v qfa[2], qfb[2];
  {
    const u16* qp = qkv + (rowbase + qaT * 64 + w * 16 + lo) * C3 + h * HDIM + g * 8;
    qfa[0] = *(const s8v*)qp;
    qfa[1] = *(const s8v*)(qp + 32);
    qp = qkv + (rowbase + qbT * 64 + w * 16 + lo) * C3 + h * HDIM + g * 8;
    qfb[0] = *(const s8v*)qp;
    qfb[1] = *(const s8v*)(qp + 32);
  }

  f4v accOa[4], accOb[4];
  float ma[4], la[4], mb[4], lb[4];
#pragma unroll
  for (int d = 0; d < 4; ++d) {
    accOa[d] = (f4v){0.f, 0.f, 0.f, 0.f};
    accOb[d] = (f4v){0.f, 0.f, 0.f, 0.f};
  }
#pragma unroll
  for (int j = 0; j < 4; ++j) { ma[j] = -1e30f; la[j] = 0.f; mb[j] = -1e30f; lb[j] = 0.f; }

  auto qcompute = [&](const s8v* qf, f4v* accO, float* m, float* l,
                      const u16* sKb, const u16* sVb, bool diag) {
    f4v accS[4];
#pragma unroll
    for (int kb = 0; kb < 4; ++kb) accS[kb] = (f4v){0.f, 0.f, 0.f, 0.f};
#pragma unroll
    for (int ks = 0; ks < 2; ++ks) {
      const int chunk = ks * 4 + g;
#pragma unroll
      for (int kb = 0; kb < 4; ++kb) {
        int row = kb * 16 + lo;
        s8v kf = *(const s8v*)&sKb[row * 64 + ((chunk ^ (row & 7)) * 8)];
        accS[kb] = __builtin_amdgcn_mfma_f32_16x16x32_bf16(qf[ks], kf, accS[kb], 0, 0, 0);
      }
    }
    float sv[4][4];
#pragma unroll
    for (int kb = 0; kb < 4; ++kb)
#pragma unroll
      for (int j = 0; j < 4; ++j)
        sv[kb][j] = accS[kb][j] * SCALE_LOG2;   // log2-domain scores
    if (diag) {                                  // uniform branch: only diag tile pays
      const int qrow = w * 16 + g * 4;
#pragma unroll
      for (int kb = 0; kb < 4; ++kb)
#pragma unroll
        for (int j = 0; j < 4; ++j)
          if (kb * 16 + lo > qrow + j) sv[kb][j] = -1e30f;
    }
    float pm[4];
#pragma unroll
    for (int j = 0; j < 4; ++j)
      pm[j] = fmaxf(fmaxf(sv[0][j], sv[1][j]), fmaxf(sv[2][j], sv[3][j]));
#pragma unroll
    for (int msk = 1; msk <= 8; msk <<= 1)
#pragma unroll
      for (int j = 0; j < 4; ++j) pm[j] = fmaxf(pm[j], __shfl_xor(pm[j], msk, 64));
    // defer-max: rescale only if some row's max grew past THR=8 (log2 domain)
    bool resc = false;
#pragma unroll
    for (int j = 0; j < 4; ++j) resc |= (pm[j] - m[j] > 8.0f);
    if (__any(resc)) {
#pragma unroll
      for (int j = 0; j < 4; ++j) {
        float mn = fmaxf(m[j], pm[j]);
        float corr = exp2f(m[j] - mn);
        m[j] = mn;
        l[j] *= corr;
#pragma unroll
        for (int d = 0; d < 4; ++d) accO[d][j] *= corr;
      }
    }
    float pr[4][4], ps[4] = {0.f, 0.f, 0.f, 0.f};
#pragma unroll
    for (int kb = 0; kb < 4; ++kb)
#pragma unroll
      for (int j = 0; j < 4; ++j) {
        pr[kb][j] = exp2f(sv[kb][j] - m[j]);   // bounded by 2^8
        ps[j] += pr[kb][j];
      }
#pragma unroll
    for (int msk = 1; msk <= 8; msk <<= 1)
#pragma unroll
      for (int j = 0; j < 4; ++j) ps[j] += __shfl_xor(ps[j], msk, 64);
#pragma unroll
    for (int j = 0; j < 4; ++j) l[j] += ps[j];
    // P -> per-wave LDS (swizzled) to reshape into A-operand layout
#pragma unroll
    for (int kb = 0; kb < 4; ++kb)
#pragma unroll
      for (int j = 0; j < 4; ++j) {
        int q = g * 4 + j;
        int col = kb * 16 + lo;
        sP[w][q * 64 + (((col >> 3) ^ (q & 7)) * 8) + (col & 7)] = f2bf(pr[kb][j]);
      }
#pragma unroll
    for (int ks = 0; ks < 2; ++ks) {
      const int chunk = ks * 4 + g;
      s8v pf = *(const s8v*)&sP[w][lo * 64 + ((chunk ^ (lo & 7)) * 8)];
#pragma unroll
      for (int db = 0; db < 4; ++db) {
        int row = db * 16 + lo;
        s8v vf = *(const s8v*)&sVb[row * 64 + ((chunk ^ (row & 7)) * 8)];
        accO[db] = __builtin_amdgcn_mfma_f32_16x16x32_bf16(pf, vf, accO[db], 0, 0, 0);
      }
    }
  };

  stage(0);
  for (int kt = 0; kt < nkt; ++kt) {
    if (kt + 1 < nkt) {
      stage(kt + 1);
      asm volatile("s_waitcnt vmcnt(4)" ::: "memory");
    } else {
      asm volatile("s_waitcnt vmcnt(0)" ::: "memory");
    }
    asm volatile("s_barrier" ::: "memory");
    const u16* sKb = sK[kt & 1];
    const u16* sVb = sV[kt & 1];
    qcompute(qfb, accOb, mb, lb, sKb, sVb, kt == qbT);
    if (kt <= qaT) qcompute(qfa, accOa, ma, la, sKb, sVb, kt == qaT);
    asm volatile("s_barrier" ::: "memory");
  }

  // epilogue: normalize, merge heads
#pragma unroll
  for (int j = 0; j < 4; ++j) {
    float ia = 1.f / la[j], ib = 1.f / lb[j];
#pragma unroll
    for (int db = 0; db < 4; ++db) {
      int qra = qaT * 64 + w * 16 + g * 4 + j;
      int qrb = qbT * 64 + w * 16 + g * 4 + j;
      int dd = h * HDIM + db * 16 + lo;
      y[(rowbase + qra) * CEMB + dd] = f2bf(accOa[db][j] * ia);
      y[(rowbase + qrb) * CEMB + dd] = f2bf(accOb[db][j] * ib);
    }
  }
}

// ---------------- launch ----------------
extern "C" void kernel_launch(void* const* d_in, const int* in_sizes, int n_in,
                              void* d_out, int out_size, void* d_ws, size_t ws_size,
                              hipStream_t stream) {
  const float* x  = (const float*)d_in[0];
  const float* Wa = (const float*)d_in[1];
  const float* Wp = (const float*)d_in[2];
  float* out = (float*)d_out;

  char* ws = (char*)d_ws;
  u16* xb   = (u16*)(ws);                       // 16 MB: x bf16 [8192][1024]
  u16* WaT  = (u16*)(ws + (16u << 20));         //  6 MB: W_attn^T bf16 [3072][1024]
  u16* WpT  = (u16*)(ws + (22u << 20));         //  2 MB: W_proj^T bf16 [1024][1024]
  u16* qkv  = (u16*)(ws + (24u << 20));         // 48 MB: qkv bf16 [8192][3072]
  u16* ybuf = (u16*)(ws + (72u << 20));         // 16 MB: y bf16 [8192][1024]
  u16* vTb  = (u16*)(ws + (88u << 20));         // 16 MB: V^T bf16 [64][64][2048]

  cvt_f32_bf16<<<dim3((MTOT * CEMB / 4 + 255) / 256), dim3(256), 0, stream>>>(
      x, xb, MTOT * CEMB / 4);
  transpose_cvt<<<dim3(C3 / 32, CEMB / 32), dim3(32, 8), 0, stream>>>(Wa, WaT, CEMB, C3);
  transpose_cvt<<<dim3(CEMB / 32, CEMB / 32), dim3(32, 8), 0, stream>>>(Wp, WpT, CEMB, CEMB);
  gemm_bt<0><<<dim3(C3 / 128, MTOT / 128), dim3(256), 0, stream>>>(
      xb, WaT, (void*)qkv, MTOT, C3, CEMB);
  vtrans<<<dim3(TSEQ / 64, 64), dim3(256), 0, stream>>>(qkv, vTb);
  flash_attn<<<dim3(64, NPAIR), dim3(256), 0, stream>>>(qkv, vTb, ybuf);
  gemm_bt<1><<<dim3(CEMB / 128, MTOT / 128), dim3(256), 0, stream>>>(
      ybuf, WpT, (void*)out, MTOT, CEMB, CEMB);
}

// Round 8
// 327.429 us; speedup vs baseline: 1.4355x; 1.4355x over previous
//
#include <hip/hip_runtime.h>

typedef __attribute__((ext_vector_type(8))) short s8v;   // 8 x bf16 (4 VGPRs)
typedef __attribute__((ext_vector_type(4))) float f4v;   // MFMA acc
typedef unsigned short u16;
typedef unsigned int u32;

#define MTOT 8192   // B*T
#define CEMB 1024
#define C3   3072
#define TSEQ 2048
#define HDIM 64
#define NQT  32     // TSEQ/64
#define NPAIR 16
#define SCALE_LOG2 0.022542110013890054f   // (1/64) * log2(e)

__device__ __forceinline__ u16 f2bf(float f) {
  u32 u = __float_as_uint(f);
  u = (u + 0x7fffu + ((u >> 16) & 1u)) >> 16;  // RNE
  return (u16)u;
}

__device__ __forceinline__ void gload_lds16(const u16* g, u16* l) {
  __builtin_amdgcn_global_load_lds(
      (const __attribute__((address_space(1))) u32*)g,
      (__attribute__((address_space(3))) u32*)l, 16, 0, 0);
}

// ---------------- elementwise f32 -> bf16 ----------------
__global__ void cvt_f32_bf16(const float* __restrict__ in, u16* __restrict__ out, int n4) {
  int i = blockIdx.x * blockDim.x + threadIdx.x;
  if (i < n4) {
    float4 a = ((const float4*)in)[i];
    ushort4 o;
    o.x = f2bf(a.x); o.y = f2bf(a.y); o.z = f2bf(a.z); o.w = f2bf(a.w);
    ((ushort4*)out)[i] = o;
  }
}

// ---------------- transpose + cast: in[R][C] f32 -> out[C][R] bf16 ----------------
__global__ void transpose_cvt(const float* __restrict__ in, u16* __restrict__ out, int R, int C) {
  __shared__ float t[32][33];
  int c0 = blockIdx.x * 32, r0 = blockIdx.y * 32;
  int tx = threadIdx.x, ty = threadIdx.y;  // (32,8)
#pragma unroll
  for (int i = 0; i < 4; ++i)
    t[ty + 8 * i][tx] = in[(long)(r0 + ty + 8 * i) * C + c0 + tx];
  __syncthreads();
#pragma unroll
  for (int i = 0; i < 4; ++i)
    out[(long)(c0 + ty + 8 * i) * R + r0 + tx] = f2bf(t[tx][ty + 8 * i]);
}

// ---------------- V transpose: qkv V-part [t][d] -> vT[bh][d][t] ----------------
__global__ void vtrans(const u16* __restrict__ qkv, u16* __restrict__ vT) {
  __shared__ u16 t[64][72];
  const int bh = blockIdx.y, b = bh >> 4, h = bh & 15;
  const int t0 = blockIdx.x * 64;
  const int tid = threadIdx.x;
  {
    int tr = tid >> 2, dc = (tid & 3) * 16;
    const u16* src = qkv + ((long)(b * TSEQ + t0 + tr)) * C3 + 2048 + h * HDIM + dc;
    *(s8v*)&t[tr][dc] = *(const s8v*)src;
    *(s8v*)&t[tr][dc + 8] = *(const s8v*)(src + 8);
  }
  __syncthreads();
  {
    int dr = tid >> 2, tc = (tid & 3) * 16;
    s8v o0, o1;
#pragma unroll
    for (int i = 0; i < 8; ++i) {
      o0[i] = (short)t[tc + i][dr];
      o1[i] = (short)t[tc + 8 + i][dr];
    }
    u16* dst = vT + ((long)(bh * HDIM + dr)) * TSEQ + t0 + tc;
    *(s8v*)dst = o0;
    *(s8v*)(dst + 8) = o1;
  }
}

// ---------------- GEMM: C[M][N] = A[M][K] * BT[N][K]^T   (bf16 in, f32 acc) ----------------
template<int OUTF32>
__global__ __launch_bounds__(256, 3)
void gemm_bt(const u16* __restrict__ A, const u16* __restrict__ BT,
             void* __restrict__ Cout, int M, int N, int K) {
  __shared__ u16 sA[128 * 64];
  __shared__ u16 sB[128 * 64];
  const int tid = threadIdx.x;
  const int lane = tid & 63;
  const int w = tid >> 6;
  const int wr = w >> 1, wc = w & 1;
  const int blockM = blockIdx.y * 128;
  const int blockN = blockIdx.x * 128;

  f4v acc[4][4];
#pragma unroll
  for (int m = 0; m < 4; ++m)
#pragma unroll
    for (int n = 0; n < 4; ++n)
      acc[m][n] = (f4v){0.f, 0.f, 0.f, 0.f};

  const u16* aptr[4];
  const u16* bptr[4];
  int ldsoff[4];
#pragma unroll
  for (int i = 0; i < 4; ++i) {
    int ch = w * 4 + i;
    int L = ch * 1024 + lane * 16;
    int row = L >> 7;
    int pc = (L >> 4) & 7;
    int c = (pc ^ (row & 7)) * 8;
    ldsoff[i] = ch * 1024;
    aptr[i] = A + (long)(blockM + row) * K + c;
    bptr[i] = BT + (long)(blockN + row) * K + c;
  }

  for (int k0 = 0; k0 < K; k0 += 64) {
    __syncthreads();
#pragma unroll
    for (int i = 0; i < 4; ++i) {
      gload_lds16(aptr[i] + k0, (u16*)((char*)sA + ldsoff[i]));
      gload_lds16(bptr[i] + k0, (u16*)((char*)sB + ldsoff[i]));
    }
    __syncthreads();
#pragma unroll
    for (int ks = 0; ks < 2; ++ks) {
      s8v af[4], bfv[4];
      const int chunk = ks * 4 + (lane >> 4);
#pragma unroll
      for (int m = 0; m < 4; ++m) {
        int row = wr * 64 + m * 16 + (lane & 15);
        af[m] = *(const s8v*)((const char*)sA + row * 128 + ((chunk ^ (row & 7)) << 4));
      }
#pragma unroll
      for (int n = 0; n < 4; ++n) {
        int row = wc * 64 + n * 16 + (lane & 15);
        bfv[n] = *(const s8v*)((const char*)sB + row * 128 + ((chunk ^ (row & 7)) << 4));
      }
#pragma unroll
      for (int m = 0; m < 4; ++m)
#pragma unroll
        for (int n = 0; n < 4; ++n)
          acc[m][n] = __builtin_amdgcn_mfma_f32_16x16x32_bf16(af[m], bfv[n], acc[m][n], 0, 0, 0);
    }
  }

  const int rl = ((lane >> 4) & 3) * 4;
  const int cl = lane & 15;
#pragma unroll
  for (int m = 0; m < 4; ++m)
#pragma unroll
    for (int n = 0; n < 4; ++n)
#pragma unroll
      for (int j = 0; j < 4; ++j) {
        long r = blockM + wr * 64 + m * 16 + rl + j;
        long c = blockN + wc * 64 + n * 16 + cl;
        float v = acc[m][n][j];
        if (OUTF32)
          ((float*)Cout)[r * N + c] = v;
        else
          ((u16*)Cout)[r * N + c] = f2bf(v);
      }
}

// ---------------- flash attention (causal, muP scale 1/64) ----------------
// Pair-balanced: block (bh, p) handles q-tiles qa=p and qb=31-p, sharing staged K/V.
// Softmax in log2 domain; defer-max rescale (THR=8); causal mask only on diag tiles.
// launch_bounds(256,3): 3 blocks/CU keeps per-XCD K/V working set ~3MB < 4MB L2.
// (4 blocks/CU measured R7: FETCH 47.6->650MB, dur 160->298us — L2 thrash.)
__global__ __launch_bounds__(256, 3)
void flash_attn(const u16* __restrict__ qkv, const u16* __restrict__ vT,
                u16* __restrict__ y) {
  __shared__ u16 sK[2][64 * 64];
  __shared__ u16 sV[2][64 * 64];
  __shared__ u16 sP[4][16 * 64];
  const int tid = threadIdx.x;
  const int lane = tid & 63;
  const int w = tid >> 6;
  const int g = lane >> 4, lo = lane & 15;
  const int bh = blockIdx.x;        // bh fastest -> all pair-blocks of a head on one XCD
  const int p = blockIdx.y;
  const int b = bh >> 4, h = bh & 15;
  const long rowbase = (long)b * TSEQ;
  const int qaT = p, qbT = NQT - 1 - p;
  const int nkt = qbT + 1;

  // staging: wave w owns chunks ch = w*2+i (i=0..1), rows w*16+i*8 .. +7
  const int srow = w * 16 + (lane >> 3);
  const int scol = ((lane & 7) ^ (lane >> 3)) * 8;  // pre-inverse-swizzled source col
  const u16* kS0 = qkv + (rowbase + srow) * C3 + 1024 + h * HDIM + scol;
  const u16* vS0 = vT + ((long)(bh * HDIM + srow)) * TSEQ + scol;
  u16* kD0 = &sK[0][w * 1024];
  u16* vD0 = &sV[0][w * 1024];

  auto stage = [&](int kt) {
    const int bufo = (kt & 1) * 4096;
    const long ka = (long)kt * 64 * C3;
    const int va = kt * 64;
#pragma unroll
    for (int i = 0; i < 2; ++i) {
      gload_lds16(kS0 + ka + i * 8 * C3, kD0 + bufo + i * 512);
      gload_lds16(vS0 + va + (long)i * 8 * TSEQ, vD0 + bufo + i * 512);
    }
  };

  s8v qfa[2], qfb[2];
  {
    const u16* qp = qkv + (rowbase + qaT * 64 + w * 16 + lo) * C3 + h * HDIM + g * 8;
    qfa[0] = *(const s8v*)qp;
    qfa[1] = *(const s8v*)(qp + 32);
    qp = qkv + (rowbase + qbT * 64 + w * 16 + lo) * C3 + h * HDIM + g * 8;
    qfb[0] = *(const s8v*)qp;
    qfb[1] = *(const s8v*)(qp + 32);
  }

  f4v accOa[4], accOb[4];
  float ma[4], la[4], mb[4], lb[4];
#pragma unroll
  for (int d = 0; d < 4; ++d) {
    accOa[d] = (f4v){0.f, 0.f, 0.f, 0.f};
    accOb[d] = (f4v){0.f, 0.f, 0.f, 0.f};
  }
#pragma unroll
  for (int j = 0; j < 4; ++j) { ma[j] = -1e30f; la[j] = 0.f; mb[j] = -1e30f; lb[j] = 0.f; }

  auto qcompute = [&](const s8v* qf, f4v* accO, float* m, float* l,
                      const u16* sKb, const u16* sVb, bool diag) {
    f4v accS[4];
#pragma unroll
    for (int kb = 0; kb < 4; ++kb) accS[kb] = (f4v){0.f, 0.f, 0.f, 0.f};
#pragma unroll
    for (int ks = 0; ks < 2; ++ks) {
      const int chunk = ks * 4 + g;
#pragma unroll
      for (int kb = 0; kb < 4; ++kb) {
        int row = kb * 16 + lo;
        s8v kf = *(const s8v*)&sKb[row * 64 + ((chunk ^ (row & 7)) * 8)];
        accS[kb] = __builtin_amdgcn_mfma_f32_16x16x32_bf16(qf[ks], kf, accS[kb], 0, 0, 0);
      }
    }
    float sv[4][4];
#pragma unroll
    for (int kb = 0; kb < 4; ++kb)
#pragma unroll
      for (int j = 0; j < 4; ++j)
        sv[kb][j] = accS[kb][j] * SCALE_LOG2;   // log2-domain scores
    if (diag) {                                  // uniform branch: only diag tile pays
      const int qrow = w * 16 + g * 4;
#pragma unroll
      for (int kb = 0; kb < 4; ++kb)
#pragma unroll
        for (int j = 0; j < 4; ++j)
          if (kb * 16 + lo > qrow + j) sv[kb][j] = -1e30f;
    }
    float pm[4];
#pragma unroll
    for (int j = 0; j < 4; ++j)
      pm[j] = fmaxf(fmaxf(sv[0][j], sv[1][j]), fmaxf(sv[2][j], sv[3][j]));
#pragma unroll
    for (int msk = 1; msk <= 8; msk <<= 1)
#pragma unroll
      for (int j = 0; j < 4; ++j) pm[j] = fmaxf(pm[j], __shfl_xor(pm[j], msk, 64));
    // defer-max: rescale only if some row's max grew past THR=8 (log2 domain)
    bool resc = false;
#pragma unroll
    for (int j = 0; j < 4; ++j) resc |= (pm[j] - m[j] > 8.0f);
    if (__any(resc)) {
#pragma unroll
      for (int j = 0; j < 4; ++j) {
        float mn = fmaxf(m[j], pm[j]);
        float corr = exp2f(m[j] - mn);
        m[j] = mn;
        l[j] *= corr;
#pragma unroll
        for (int d = 0; d < 4; ++d) accO[d][j] *= corr;
      }
    }
    float pr[4][4], ps[4] = {0.f, 0.f, 0.f, 0.f};
#pragma unroll
    for (int kb = 0; kb < 4; ++kb)
#pragma unroll
      for (int j = 0; j < 4; ++j) {
        pr[kb][j] = exp2f(sv[kb][j] - m[j]);   // bounded by 2^8
        ps[j] += pr[kb][j];
      }
#pragma unroll
    for (int msk = 1; msk <= 8; msk <<= 1)
#pragma unroll
      for (int j = 0; j < 4; ++j) ps[j] += __shfl_xor(ps[j], msk, 64);
#pragma unroll
    for (int j = 0; j < 4; ++j) l[j] += ps[j];
    // P -> per-wave LDS (swizzled) to reshape into A-operand layout
#pragma unroll
    for (int kb = 0; kb < 4; ++kb)
#pragma unroll
      for (int j = 0; j < 4; ++j) {
        int q = g * 4 + j;
        int col = kb * 16 + lo;
        sP[w][q * 64 + (((col >> 3) ^ (q & 7)) * 8) + (col & 7)] = f2bf(pr[kb][j]);
      }
#pragma unroll
    for (int ks = 0; ks < 2; ++ks) {
      const int chunk = ks * 4 + g;
      s8v pf = *(const s8v*)&sP[w][lo * 64 + ((chunk ^ (lo & 7)) * 8)];
#pragma unroll
      for (int db = 0; db < 4; ++db) {
        int row = db * 16 + lo;
        s8v vf = *(const s8v*)&sVb[row * 64 + ((chunk ^ (row & 7)) * 8)];
        accO[db] = __builtin_amdgcn_mfma_f32_16x16x32_bf16(pf, vf, accO[db], 0, 0, 0);
      }
    }
  };

  stage(0);
  for (int kt = 0; kt < nkt; ++kt) {
    if (kt + 1 < nkt) {
      stage(kt + 1);
      asm volatile("s_waitcnt vmcnt(4)" ::: "memory");
    } else {
      asm volatile("s_waitcnt vmcnt(0)" ::: "memory");
    }
    asm volatile("s_barrier" ::: "memory");
    const u16* sKb = sK[kt & 1];
    const u16* sVb = sV[kt & 1];
    qcompute(qfb, accOb, mb, lb, sKb, sVb, kt == qbT);
    if (kt <= qaT) qcompute(qfa, accOa, ma, la, sKb, sVb, kt == qaT);
    asm volatile("s_barrier" ::: "memory");
  }

  // epilogue: normalize, merge heads
#pragma unroll
  for (int j = 0; j < 4; ++j) {
    float ia = 1.f / la[j], ib = 1.f / lb[j];
#pragma unroll
    for (int db = 0; db < 4; ++db) {
      int qra = qaT * 64 + w * 16 + g * 4 + j;
      int qrb = qbT * 64 + w * 16 + g * 4 + j;
      int dd = h * HDIM + db * 16 + lo;
      y[(rowbase + qra) * CEMB + dd] = f2bf(accOa[db][j] * ia);
      y[(rowbase + qrb) * CEMB + dd] = f2bf(accOb[db][j] * ib);
    }
  }
}

// ---------------- launch ----------------
extern "C" void kernel_launch(void* const* d_in, const int* in_sizes, int n_in,
                              void* d_out, int out_size, void* d_ws, size_t ws_size,
                              hipStream_t stream) {
  const float* x  = (const float*)d_in[0];
  const float* Wa = (const float*)d_in[1];
  const float* Wp = (const float*)d_in[2];
  float* out = (float*)d_out;

  char* ws = (char*)d_ws;
  u16* xb   = (u16*)(ws);                       // 16 MB: x bf16 [8192][1024]
  u16* WaT  = (u16*)(ws + (16u << 20));         //  6 MB: W_attn^T bf16 [3072][1024]
  u16* WpT  = (u16*)(ws + (22u << 20));         //  2 MB: W_proj^T bf16 [1024][1024]
  u16* qkv  = (u16*)(ws + (24u << 20));         // 48 MB: qkv bf16 [8192][3072]
  u16* ybuf = (u16*)(ws + (72u << 20));         // 16 MB: y bf16 [8192][1024]
  u16* vTb  = (u16*)(ws + (88u << 20));         // 16 MB: V^T bf16 [64][64][2048]

  cvt_f32_bf16<<<dim3((MTOT * CEMB / 4 + 255) / 256), dim3(256), 0, stream>>>(
      x, xb, MTOT * CEMB / 4);
  transpose_cvt<<<dim3(C3 / 32, CEMB / 32), dim3(32, 8), 0, stream>>>(Wa, WaT, CEMB, C3);
  transpose_cvt<<<dim3(CEMB / 32, CEMB / 32), dim3(32, 8), 0, stream>>>(Wp, WpT, CEMB, CEMB);
  gemm_bt<0><<<dim3(C3 / 128, MTOT / 128), dim3(256), 0, stream>>>(
      xb, WaT, (void*)qkv, MTOT, C3, CEMB);
  vtrans<<<dim3(TSEQ / 64, 64), dim3(256), 0, stream>>>(qkv, vTb);
  flash_attn<<<dim3(64, NPAIR), dim3(256), 0, stream>>>(qkv, vTb, ybuf);
  gemm_bt<1><<<dim3(CEMB / 128, MTOT / 128), dim3(256), 0, stream>>>(
      ybuf, WpT, (void*)out, MTOT, CEMB, CEMB);
}